// Round 3
// 5069.802 us; speedup vs baseline: 1.3084x; 1.3084x over previous
//
#include <hip/hip_runtime.h>
#include <hip/hip_bf16.h>

typedef __attribute__((ext_vector_type(8))) short short8;
typedef __attribute__((ext_vector_type(4))) float f32x4;

// Problem dims
#define NB 64      // batch
#define NS 1024    // seq
#define ND 512     // input dim
#define NH 512     // hidden
#define NG 2048    // 4*NH gate columns
#define M1 65536   // NB*NS rows of the input-projection GEMM

// ws layout (bytes)
#define OFF_A    0L                      // A bf16 [65536][512]           64 MB
#define OFF_XG   67108864L               // xg bf16 [1024][64][2048]     256 MB
#define OFF_WXT  335544320L              // Wxt bf16 [2048][512]           2 MB
#define OFF_WHT  337641472L              // Wht bf16 [2048][512]           2 MB
#define OFF_BC   339738624L              // bcat f32 [2048]                8 KB
#define OFF_HB   339746816L              // hb u32 [8 grp][2][8][256]    128 KB
#define OFF_BAR  339877888L              // ctrl u32: flags[8][32]         1 KB

#define OUT_HF   33554432L               // d_out offset of h_final (floats)
#define OUT_CF   33587200L               // d_out offset of c_final

static __device__ __forceinline__ ushort f2bf(float x) {
  union { float f; unsigned u; } v; v.f = x;
  unsigned r = (v.u + 0x7FFFu + ((v.u >> 16) & 1u)) >> 16;
  return (ushort)r;
}
static __device__ __forceinline__ float bf2f(ushort x) {
  union { unsigned u; float f; } v; v.u = ((unsigned)x) << 16; return v.f;
}
static __device__ __forceinline__ float sigm(float x) {
  return 1.0f / (1.0f + __expf(-x));
}
static __device__ __forceinline__ float tanh_fast(float x) {
  return 2.0f / (1.0f + __expf(-2.0f * x)) - 1.0f;
}

// ---------- phase 0a: fp32 -> bf16 convert of inputs ----------
__global__ __launch_bounds__(256) void cvt_in_k(const float* __restrict__ in,
                                                ushort* __restrict__ out) {
  long i = ((long)blockIdx.x * 256 + threadIdx.x) * 8;
  const float4* p = (const float4*)(in + i);
  float4 a = p[0], b = p[1];
  short8 o;
  o[0] = (short)f2bf(a.x); o[1] = (short)f2bf(a.y);
  o[2] = (short)f2bf(a.z); o[3] = (short)f2bf(a.w);
  o[4] = (short)f2bf(b.x); o[5] = (short)f2bf(b.y);
  o[6] = (short)f2bf(b.z); o[7] = (short)f2bf(b.w);
  *(short8*)(out + i) = o;
}

// ---------- phase 0b: transpose+convert weights, pack biases ----------
__global__ __launch_bounds__(256) void prep_w_k(
    const float* __restrict__ Wxi, const float* __restrict__ Whi, const float* __restrict__ bi,
    const float* __restrict__ Wxf, const float* __restrict__ Whf, const float* __restrict__ bff,
    const float* __restrict__ Wxo, const float* __restrict__ Who, const float* __restrict__ bo,
    const float* __restrict__ Wxc, const float* __restrict__ Whc, const float* __restrict__ bc,
    ushort* __restrict__ Wxt, ushort* __restrict__ Wht, float* __restrict__ bcat) {
  int t = blockIdx.x * 256 + threadIdx.x;   // 0 .. 2048*512-1
  int n = t >> 9, k = t & 511;
  int g = n >> 9, col = n & 511;
  const float* wx = (g == 0) ? Wxi : (g == 1) ? Wxf : (g == 2) ? Wxo : Wxc;
  const float* wh = (g == 0) ? Whi : (g == 1) ? Whf : (g == 2) ? Who : Whc;
  Wxt[t] = f2bf(wx[k * 512 + col]);
  Wht[t] = f2bf(wh[k * 512 + col]);
  if (t < 2048) {
    int g2 = t >> 9;
    const float* bp = (g2 == 0) ? bi : (g2 == 1) ? bff : (g2 == 2) ? bo : bc;
    bcat[t] = bp[t & 511];
  }
}

// ---------- phase 1: xg = A @ Wxt^T + b  (bf16 MFMA, 128x128 tiles, BK=32) ----------
__global__ __launch_bounds__(256) void gemm_x_k(const ushort* __restrict__ A,
                                                const ushort* __restrict__ Bt,
                                                const float* __restrict__ bcat,
                                                ushort* __restrict__ xg) {
  __shared__ ushort As[128 * 40];
  __shared__ ushort Bs[128 * 40];
  const int mbase = blockIdx.x * 128;
  const int nbase = blockIdx.y * 128;
  const int tid = threadIdx.x;
  const int lane = tid & 63, wave = tid >> 6;
  const int l15 = lane & 15, q = lane >> 4;
  const int wm = (wave & 1) * 64, wn = (wave >> 1) * 64;

  f32x4 acc[4][4];
#pragma unroll
  for (int j = 0; j < 4; ++j) {
    float bv = bcat[nbase + wn + j * 16 + l15];
#pragma unroll
    for (int i = 0; i < 4; ++i) acc[i][j] = (f32x4){bv, bv, bv, bv};
  }

  const int sr = tid >> 2;
  const int skk = (tid & 3) * 8;

  for (int kt = 0; kt < 16; ++kt) {
    const int kb = kt * 32;
#pragma unroll
    for (int pass = 0; pass < 2; ++pass) {
      int rr = sr + pass * 64;
      *(short8*)&As[rr * 40 + skk] = *(const short8*)&A[(long)(mbase + rr) * 512 + kb + skk];
      *(short8*)&Bs[rr * 40 + skk] = *(const short8*)&Bt[(long)(nbase + rr) * 512 + kb + skk];
    }
    __syncthreads();
    short8 af[4], bfr[4];
#pragma unroll
    for (int i = 0; i < 4; ++i)
      af[i] = *(const short8*)&As[(wm + i * 16 + l15) * 40 + q * 8];
#pragma unroll
    for (int j = 0; j < 4; ++j)
      bfr[j] = *(const short8*)&Bs[(wn + j * 16 + l15) * 40 + q * 8];
#pragma unroll
    for (int i = 0; i < 4; ++i)
#pragma unroll
      for (int j = 0; j < 4; ++j)
        acc[i][j] = __builtin_amdgcn_mfma_f32_16x16x32_bf16(af[i], bfr[j], acc[i][j], 0, 0, 0);
    __syncthreads();
  }

#pragma unroll
  for (int i = 0; i < 4; ++i) {
#pragma unroll
    for (int r = 0; r < 4; ++r) {
      int m = mbase + wm + i * 16 + q * 4 + r;
      int b = m >> 10, s = m & 1023;
      long rowoff = ((long)(s * 64 + b)) * 2048;
#pragma unroll
      for (int j = 0; j < 4; ++j) {
        int n = nbase + wn + j * 16 + l15;
        xg[rowoff + n] = f2bf(acc[i][j][r]);
      }
    }
  }
}

// ---------- phase 2: persistent recurrence, 8 independent 16-WG groups ----------
// 128 WGs = 8 groups x 16 roles. Group g = wg&7 owns batches [8g,8g+8) (M=16
// MFMA tile, rows 8..15 zero-padded); role r = wg>>3 owns h-cols [32r,32r+32).
// Batches independent across groups -> NO inter-group sync ever. Intra-group
// h exchange is the PROVEN protocol verbatim (AGENT-scope relaxed atomics,
// MALL coherence point, compiler drains): h stores -> __syncthreads (vmcnt
// drain) -> flag publish -> out stores (retire off critical path) -> xg
// prefetch -> spin(16 group-private flags) -> __syncthreads.
// vs the 64-WG all-to-all: 16x fewer pollers/writers per flag line (256 vs
// 4096 / 16 vs 63) and max-over-16 instead of max-over-64 jitter.
__global__ __launch_bounds__(256, 1) void lstm_rec_k(const ushort* __restrict__ xg,
                                                     const ushort* __restrict__ Wht,
                                                     float* __restrict__ out,
                                                     unsigned* hb, unsigned* ctrl) {
  const int wg = blockIdx.x;          // 0..127
  const int g = wg & 7, r = wg >> 3;  // group, role
  const int tid = threadIdx.x;
  const int wave = tid >> 6, lane = tid & 63;
  const int l15 = lane & 15, q = lane >> 4;

  unsigned* fl  = ctrl + g * 32;      // 128B per group: private flag line
  unsigned* hbg = hb + g * 4096;      // 16KB per group: [2 parity][8 rows][256 u32]
  const ushort* xgg = xg + (long)g * 8 * 2048;  // group's batch-0 column

  // --- B fragments: this wave's 32 gate-cols (gates packed pairwise), pinned ---
  // B[k][n]: n(loc) = lane&15, k = kt*32 + q*8 + 0..7
  short8 bfrag[2][16];
  int gcol[2];
#pragma unroll
  for (int p = 0; p < 2; ++p) {
    int nloc = p * 16 + l15;
    gcol[p] = (nloc >> 3) * 512 + r * 32 + wave * 8 + (nloc & 7);
#pragma unroll
    for (int kt = 0; kt < 16; ++kt)
      bfrag[p][kt] = *(const short8*)&Wht[(long)gcol[p] * 512 + kt * 32 + q * 8];
  }
#pragma unroll
  for (int p = 0; p < 2; ++p)
#pragma unroll
    for (int kt = 0; kt < 16; ++kt)
      asm volatile("" : "+v"(bfrag[p][kt]));

  // zero h_0 (parity 0): role r zeroes its 16 u32-cols x 8 rows
  if (tid < 128) {
    int row = tid >> 4, c = tid & 15;
    __hip_atomic_store(&hbg[row * 256 + r * 16 + c], 0u, __ATOMIC_RELAXED,
                       __HIP_MEMORY_SCOPE_AGENT);
  }
  __syncthreads();                    // drains vmcnt: zeros ack'd at MALL
  if (tid == 0)
    __hip_atomic_store(&fl[r], 1u, __ATOMIC_RELAXED, __HIP_MEMORY_SCOPE_AGENT);

  // prefetch xg[t=0] under the spin
  float xpre[2][4] = {{0.f, 0.f, 0.f, 0.f}, {0.f, 0.f, 0.f, 0.f}};
  if (q < 2) {
#pragma unroll
    for (int p = 0; p < 2; ++p)
#pragma unroll
      for (int rr = 0; rr < 4; ++rr)
        xpre[p][rr] = bf2f(xgg[(long)(q * 4 + rr) * 2048 + gcol[p]]);
  }
  if (wave == 0 && lane < 16) {
    while (__hip_atomic_load(&fl[lane], __ATOMIC_RELAXED,
                             __HIP_MEMORY_SCOPE_AGENT) < 1u) {}
  }
  __syncthreads();

  const bool wr = (lane & 8) == 0;          // gate-dedup writer lanes
  const bool wrp = wr && ((lane & 1) == 0); // pair writer lanes (u32 / float2)
  float c4[4] = {0.f, 0.f, 0.f, 0.f};
  float hsave[4] = {0.f, 0.f, 0.f, 0.f};
  float hpsave[4] = {0.f, 0.f, 0.f, 0.f};

  for (int t = 0; t < 1024; ++t) {
    const unsigned* hrow = hbg + (t & 1) * 2048;

    // A fragments: A[m][k], m = lane&15 (batch row; 8..15 zero pad), k = kt*32+q*8+j
    union { unsigned long long u[2]; short8 s8; } afu[16];
    if (l15 < 8) {
      const unsigned* base = hrow + l15 * 256 + q * 4;
#pragma unroll
      for (int kt = 0; kt < 16; ++kt) {
        const unsigned long long* p = (const unsigned long long*)(base + kt * 16);
        afu[kt].u[0] = __hip_atomic_load(p, __ATOMIC_RELAXED, __HIP_MEMORY_SCOPE_AGENT);
        afu[kt].u[1] = __hip_atomic_load(p + 1, __ATOMIC_RELAXED, __HIP_MEMORY_SCOPE_AGENT);
      }
    } else {
#pragma unroll
      for (int kt = 0; kt < 16; ++kt) { afu[kt].u[0] = 0ull; afu[kt].u[1] = 0ull; }
    }

    f32x4 acc[2];
#pragma unroll
    for (int p = 0; p < 2; ++p)
#pragma unroll
      for (int rr = 0; rr < 4; ++rr)
        acc[p][rr] = xpre[p][rr];

#pragma unroll
    for (int kt = 0; kt < 16; ++kt) {
      acc[0] = __builtin_amdgcn_mfma_f32_16x16x32_bf16(afu[kt].s8, bfrag[0][kt], acc[0], 0, 0, 0);
      acc[1] = __builtin_amdgcn_mfma_f32_16x16x32_bf16(afu[kt].s8, bfrag[1][kt], acc[1], 0, 0, 0);
    }

    // elementwise: lane (bit3=0) has i (acc0), o (acc1); partner lane^8 has f, g.
    unsigned* hdst = hbg + ((t + 1) & 1) * 2048;
#pragma unroll
    for (int rr = 0; rr < 4; ++rr) {
      float a0 = acc[0][rr], a1 = acc[1][rr];
      float o0 = __shfl_xor(a0, 8);
      float o1 = __shfl_xor(a1, 8);
      float pi = wr ? a0 : o0;
      float pf = wr ? o0 : a0;
      float po = wr ? a1 : o1;
      float pg = wr ? o1 : a1;
      float ig = sigm(pi), fg = sigm(pf), og = sigm(po), gg = tanh_fast(pg);
      float cc = fg * c4[rr] + ig * gg;
      c4[rr] = cc;
      float hn = og * tanh_fast(cc);
      float hnp = __shfl_xor(hn, 1);        // partner col's h
      hsave[rr] = hn;
      hpsave[rr] = hnp;
      if (wrp && q < 2) {
        unsigned pack = (unsigned)f2bf(hn) | ((unsigned)f2bf(hnp) << 16);
        __hip_atomic_store(&hdst[(q * 4 + rr) * 256 + r * 16 + wave * 4 + ((lane & 6) >> 1)],
                           pack, __ATOMIC_RELAXED, __HIP_MEMORY_SCOPE_AGENT);
      }
    }

    if (t < 1023) {
      __syncthreads();                      // drains vmcnt(0): h stores ack'd at MALL
      if (tid == 0)
        __hip_atomic_store(&fl[r], (unsigned)(t + 2), __ATOMIC_RELAXED,
                           __HIP_MEMORY_SCOPE_AGENT);
    }

    // out stores after flag publish: retire during next step, off critical path
    if (wrp && q < 2) {
#pragma unroll
      for (int rr = 0; rr < 4; ++rr)
        *(float2*)&out[(long)(g * 8 + q * 4 + rr) * (NS * NH) + (long)t * NH +
                       r * 32 + wave * 8 + (lane & 6)] =
            make_float2(hsave[rr], hpsave[rr]);
    }

    if (t < 1023) {
      // prefetch next step's xg under the spin (read-only, cached)
      long xb2 = ((long)(t + 1) * 64) * 2048;
      if (q < 2) {
#pragma unroll
        for (int p = 0; p < 2; ++p)
#pragma unroll
          for (int rr = 0; rr < 4; ++rr)
            xpre[p][rr] = bf2f(xgg[xb2 + (long)(q * 4 + rr) * 2048 + gcol[p]]);
      }
      if (wave == 0 && lane < 16) {
        unsigned tgt = (unsigned)(t + 2);
        while (__hip_atomic_load(&fl[lane], __ATOMIC_RELAXED,
                                 __HIP_MEMORY_SCOPE_AGENT) < tgt) {}
      }
      __syncthreads();
    }
  }

  // final h / c state (t = 1023 values still in registers)
  if (wr && q < 2) {
    int hcol = r * 32 + wave * 8 + (lane & 7);
#pragma unroll
    for (int rr = 0; rr < 4; ++rr) {
      int b = g * 8 + q * 4 + rr;
      out[OUT_HF + (long)b * 512 + hcol] = hsave[rr];
      out[OUT_CF + (long)b * 512 + hcol] = c4[rr];
    }
  }
}

extern "C" void kernel_launch(void* const* d_in, const int* in_sizes, int n_in,
                              void* d_out, int out_size, void* d_ws, size_t ws_size,
                              hipStream_t stream) {
  const float* inputs = (const float*)d_in[0];
  const float* Wxi = (const float*)d_in[1];
  const float* Whi = (const float*)d_in[2];
  const float* bi  = (const float*)d_in[3];
  const float* Wxf = (const float*)d_in[4];
  const float* Whf = (const float*)d_in[5];
  const float* bff = (const float*)d_in[6];
  const float* Wxo = (const float*)d_in[7];
  const float* Who = (const float*)d_in[8];
  const float* bo  = (const float*)d_in[9];
  const float* Wxc = (const float*)d_in[10];
  const float* Whc = (const float*)d_in[11];
  const float* bc  = (const float*)d_in[12];

  char* ws = (char*)d_ws;
  ushort*  Abf  = (ushort*)(ws + OFF_A);
  ushort*  xgp  = (ushort*)(ws + OFF_XG);
  ushort*  Wxt  = (ushort*)(ws + OFF_WXT);
  ushort*  Whtp = (ushort*)(ws + OFF_WHT);
  float*   bcat = (float*)(ws + OFF_BC);
  unsigned* hb  = (unsigned*)(ws + OFF_HB);
  unsigned* ctrl = (unsigned*)(ws + OFF_BAR);

  hipMemsetAsync(ctrl, 0, 1024, stream);   // flags[8][32]

  cvt_in_k<<<16384, 256, 0, stream>>>(inputs, Abf);
  prep_w_k<<<4096, 256, 0, stream>>>(Wxi, Whi, bi, Wxf, Whf, bff,
                                     Wxo, Who, bo, Wxc, Whc, bc,
                                     Wxt, Whtp, bcat);
  dim3 g1(M1 / 128, NG / 128);                                      // 512 x 16
  gemm_x_k<<<g1, 256, 0, stream>>>(Abf, Wxt, bcat, xgp);
  lstm_rec_k<<<128, 256, 0, stream>>>(xgp, Whtp, (float*)d_out, hb, ctrl);
}